// Round 2
// baseline (376.064 us; speedup 1.0000x reference)
//
#include <hip/hip_runtime.h>
#include <stdint.h>

#define BSZ 8
#define SEQ 2048
#define DM 1024
#define DS 16
#define MROWS (BSZ * SEQ)  // 16384
#define CHK 32             // chunks over SEQ
#define CLEN (SEQ / CHK)   // 64 steps per chunk
#define LOG2E 1.4426950408889634f

// gemm tile
#define BM 256
#define BN 256
#define BK 64

typedef __bf16 bf16x8 __attribute__((ext_vector_type(8)));
typedef float f32x4 __attribute__((ext_vector_type(4)));

union F4 { float4 v; float f[4]; };

// round-to-nearest-even fp32 -> bf16 (bit pattern)
__device__ __forceinline__ uint16_t f2bf(float f) {
  uint32_t u = __float_as_uint(f);
  u += 0x7FFFu + ((u >> 16) & 1u);
  return (uint16_t)(u >> 16);
}

// pack two floats as f16 pair in a uint32 (a = lo, b = hi)
__device__ __forceinline__ uint32_t pack_h2(float a, float b) {
  _Float16 ha = (_Float16)a, hb = (_Float16)b;
  uint16_t ua = __builtin_bit_cast(uint16_t, ha);
  uint16_t ub = __builtin_bit_cast(uint16_t, hb);
  return (uint32_t)ua | ((uint32_t)ub << 16);
}
__device__ __forceinline__ float unpack_lo(uint32_t v) {
  return (float)__builtin_bit_cast(_Float16, (uint16_t)(v & 0xffffu));
}
__device__ __forceinline__ float unpack_hi(uint32_t v) {
  return (float)__builtin_bit_cast(_Float16, (uint16_t)(v >> 16));
}

// async global->LDS, 16B per lane; LDS base must be wave-uniform.
__device__ __forceinline__ void async_cp16(const void* g, void* l) {
  __builtin_amdgcn_global_load_lds(
      (const __attribute__((address_space(1))) uint32_t*)(uintptr_t)g,
      (__attribute__((address_space(3))) uint32_t*)(uint32_t)(uintptr_t)l,
      16, 0, 0);
}

// ---------------- dt_w fp32 -> bf16 ----------------
__global__ __launch_bounds__(256) void wprep_kernel(
    const float* __restrict__ w, uint16_t* __restrict__ wb) {
  int t = blockIdx.x * 256 + threadIdx.x;  // DM*DM/4 threads
  F4 u; u.v = *(const float4*)(w + (size_t)t * 4);
  uint32_t lo = f2bf(u.f[0]) | ((uint32_t)f2bf(u.f[1]) << 16);
  uint32_t hi = f2bf(u.f[2]) | ((uint32_t)f2bf(u.f[3]) << 16);
  *(uint2*)(wb + (size_t)t * 4) = make_uint2(lo, hi);
}

// ---------------- scan parameter prep ----------------
__global__ __launch_bounds__(256) void aprep_kernel(
    const float* __restrict__ a_log, const float* __restrict__ bm,
    const float* __restrict__ cm, float* __restrict__ A2c,
    float* __restrict__ A2t, float* __restrict__ cb2) {
  int e = blockIdx.x * 256 + threadIdx.x;  // DM*DS threads
  float a = a_log[e];
  float A2 = -log1pf(__expf(a)) * LOG2E;
  A2c[e] = A2;
  cb2[e] = bm[e] * cm[e];
  int c = e >> 4, d = e & 15;
  int j = d >> 2, i = d & 3;
  A2t[((size_t)j * DM + c) * 4 + i] = A2;
}

// ---------------- depthwise conv k=3 pad=1 -> bf16 xf ----------------
__global__ __launch_bounds__(256) void conv_kernel(
    const float* __restrict__ x, const float* __restrict__ cw,
    const float* __restrict__ cb, uint16_t* __restrict__ xf) {
  int t = blockIdx.x * 256 + threadIdx.x;  // MROWS*DM/4 threads
  int cg = t & (DM / 4 - 1);
  int bn = t >> 8;
  int n = bn & (SEQ - 1);
  int c0 = cg * 4;
  const float* row = x + (size_t)bn * DM + c0;
  F4 xm, xc, xp;
  xm.v = make_float4(0.f, 0.f, 0.f, 0.f);
  xp.v = make_float4(0.f, 0.f, 0.f, 0.f);
  xc.v = *(const float4*)row;
  if (n > 0)       xm.v = *(const float4*)(row - DM);
  if (n < SEQ - 1) xp.v = *(const float4*)(row + DM);
  uint16_t o[4];
#pragma unroll
  for (int j = 0; j < 4; ++j) {
    int c = c0 + j;
    float v = cw[c * 3 + 0] * xm.f[j] + cw[c * 3 + 1] * xc.f[j] +
              cw[c * 3 + 2] * xp.f[j] + cb[c];
    o[j] = f2bf(v);
  }
  uint32_t lo = o[0] | ((uint32_t)o[1] << 16);
  uint32_t hi = o[2] | ((uint32_t)o[3] << 16);
  *(uint2*)(xf + (size_t)bn * DM + c0) = make_uint2(lo, hi);
}

// ---------------- dt GEMM + fused epilogue -> packed (u, dt) f16x2 ----------------
// NT GEMM, 256x256 tile, BK=64, 8 waves 2x4, 16x16x32 bf16 MFMA.
// LDS double-buffered (128 KiB); COUNTED vmcnt(8) so next tile's 8
// global_load_lds stay in flight across the barrier (never drain to 0 in
// the main loop -> T3/T4). LDS k-chunk XOR swizzle (bank-conflict-free,
// verified 0 conflicts at 128x128). setprio(1) around MFMA clusters (T5).
// Epilogue xf comes from a REGISTER STASH captured out of the As tile at
// the wave-uniform iteration t == (n0+wn*64)/64 (output cols index A's K
// dim) -> no global re-read of A.
// XCD-aware bijective block swizzle: 256 blocks, 8 XCDs -> XCD j owns
// logical [j*32,(j+1)*32) = 8 m-panels x 4 n-blocks -> A panels L2-local.
__global__ __launch_bounds__(512) void gemm_kernel(
    const uint16_t* __restrict__ A,   // MROWS x DM bf16 (xf)
    const uint16_t* __restrict__ B,   // DM x DM bf16 (dt_w)
    const float* __restrict__ bias,   // DM (dt_b)
    uint32_t* __restrict__ ud) {      // MROWS x DM packed f16x2 (u, dt)
  __shared__ __align__(16) uint16_t As[2][BM * BK];
  __shared__ __align__(16) uint16_t Bs[2][BN * BK];
  const int tid = threadIdx.x;
  const int w = tid >> 6;             // 0..7
  const int L = tid & 63;
  const int wm = w & 1, wn = w >> 1;  // 2 (M) x 4 (N) waves
  const int lane15 = L & 15, q = L >> 4;

  // XCD swizzle (bijective; 256 = 8*32)
  const int flat = blockIdx.y * gridDim.x + blockIdx.x;  // [0,256)
  const int swz = (flat & 7) * 32 + (flat >> 3);
  const int m0 = (swz >> 2) * BM;    // 64 m-panels
  const int n0 = (swz & 3) * BN;     // 4 n-blocks

  const int lr = L >> 3;                 // row-in-8 for staging
  const int lc = ((L & 7) ^ lr) * 8;     // swizzled source k-chunk (16B)
  const int r7 = lane15 & 7;             // reader row&7

  f32x4 acc[8][4] = {};
  uint32_t xst[8][4][2];                 // xf stash: [mi][ni][rpair]
  const int tstar = (n0 + wn * 64) >> 6; // wave-uniform stash iteration

  auto stage = [&](int kt, int p) {
#pragma unroll
    for (int r = 0; r < 4; ++r) {
      int R = (r * 8 + w) * 8;  // wave-uniform LDS row base
      async_cp16(A + (size_t)(m0 + R + lr) * DM + kt + lc, &As[p][R * 64]);
    }
#pragma unroll
    for (int r = 0; r < 4; ++r) {
      int R = (r * 8 + w) * 8;
      async_cp16(B + (size_t)(n0 + R + lr) * DM + kt + lc, &Bs[p][R * 64]);
    }
  };

  stage(0, 0);    // 8 loads -> buf0
  stage(BK, 1);   // 8 loads -> buf1   (16 in flight)

  for (int t = 0; t < DM / BK; ++t) {  // 16 K-tiles
    const int p = t & 1;
    // tile t's 8 loads are the oldest; leave tile t+1's 8 in flight.
    if (t < DM / BK - 1)
      asm volatile("s_waitcnt vmcnt(8)\ns_barrier" ::: "memory");
    else
      asm volatile("s_waitcnt vmcnt(0)\ns_barrier" ::: "memory");

    if (t == tstar) {  // wave-uniform: capture xf for the epilogue
#pragma unroll
      for (int mi = 0; mi < 8; ++mi)
#pragma unroll
        for (int ni = 0; ni < 4; ++ni)
#pragma unroll
          for (int rp = 0; rp < 2; ++rp) {
            int row0 = wm * 128 + mi * 16 + q * 4 + rp * 2;
            int row1 = row0 + 1;
            int cc = ni * 16 + lane15;  // in [0,64)
            uint32_t e0 =
                As[p][row0 * 64 + (((cc >> 3) ^ (row0 & 7)) << 3) + (cc & 7)];
            uint32_t e1 =
                As[p][row1 * 64 + (((cc >> 3) ^ (row1 & 7)) << 3) + (cc & 7)];
            xst[mi][ni][rp] = e0 | (e1 << 16);
          }
    }

    // B fragments for all 4 ni, both k-halves
    bf16x8 bfr[4][2];
#pragma unroll
    for (int ni = 0; ni < 4; ++ni)
#pragma unroll
      for (int ks = 0; ks < 2; ++ks)
        bfr[ni][ks] = *(const bf16x8*)(&Bs[p][(wn * 64 + ni * 16 + lane15) * 64 +
                                              ((((ks << 2) + q) ^ r7) << 3)]);

    // 4 phases over mi-pairs, 16 MFMA each
#pragma unroll
    for (int f = 0; f < 4; ++f) {
      bf16x8 af[2][2];
#pragma unroll
      for (int u2 = 0; u2 < 2; ++u2)
#pragma unroll
        for (int ks = 0; ks < 2; ++ks)
          af[u2][ks] = *(const bf16x8*)(&As[p][(wm * 128 + (f * 2 + u2) * 16 +
                                                lane15) * 64 +
                                               ((((ks << 2) + q) ^ r7) << 3)]);
      __builtin_amdgcn_s_setprio(1);
#pragma unroll
      for (int u2 = 0; u2 < 2; ++u2)
#pragma unroll
        for (int ni = 0; ni < 4; ++ni)
#pragma unroll
          for (int ks = 0; ks < 2; ++ks)
            acc[f * 2 + u2][ni] = __builtin_amdgcn_mfma_f32_16x16x32_bf16(
                af[u2][ks], bfr[ni][ks], acc[f * 2 + u2][ni], 0, 0, 0);
      __builtin_amdgcn_s_setprio(0);
    }

    // all waves done reading buf[p] -> safe to overwrite
    asm volatile("s_barrier" ::: "memory");
    if (t < DM / BK - 2) stage((t + 2) * BK, p);
  }

  // epilogue: D layout col=lane&15, row=q*4+reg. sigmoid + u=dt*xf.
#pragma unroll
  for (int ni = 0; ni < 4; ++ni) {
    int col = n0 + wn * 64 + ni * 16 + lane15;
    float db = bias[col];
#pragma unroll
    for (int mi = 0; mi < 8; ++mi) {
      int rowb = m0 + wm * 128 + mi * 16 + q * 4;
#pragma unroll
      for (int r = 0; r < 4; ++r) {
        size_t idx = (size_t)(rowb + r) * DM + col;
        float z = acc[mi][ni][r] + db;
        float dtv = 0.099f / (1.f + __expf(-z)) + 0.001f;
        uint32_t pk = xst[mi][ni][r >> 1];
        uint32_t bits = (r & 1) ? (pk & 0xffff0000u) : (pk << 16);
        float xfv = __uint_as_float(bits);
        ud[idx] = pack_h2(dtv * xfv, dtv);
      }
    }
  }
}

// ---------------- chunked selective scan (scaled state s~) ----------------
// lane = channel; one packed uint32 (u, dt) load per step.
// F layout d-plane-major: F[(((b*CHK+k)*4 + j)*DM + c)*4 + i], d = j*4+i.

__global__ __launch_bounds__(256) void scan_part1(
    const uint32_t* __restrict__ ud, const float* __restrict__ A2c,
    float* __restrict__ F, float* __restrict__ Sdt) {
  const int c = blockIdx.x * 256 + threadIdx.x;
  const int k = blockIdx.y;
  const int b = blockIdx.z;
  const int n0 = k * CLEN;

  float A2[DS], s[DS];
#pragma unroll
  for (int j = 0; j < 4; ++j) {
    F4 ua; ua.v = *(const float4*)(A2c + (size_t)c * DS + j * 4);
#pragma unroll
    for (int i = 0; i < 4; ++i) {
      A2[j * 4 + i] = ua.f[i];
      s[j * 4 + i] = 0.f;
    }
  }

  const uint32_t* up = ud + ((size_t)b * SEQ + n0) * DM + c;
  uint32_t c0 = up[0];
  uint32_t c1 = up[DM];
  uint32_t c2 = up[2 * DM];
  float sdt = 0.f;

#pragma unroll 4
  for (int t = 0; t < CLEN; ++t) {
    int tn = (t + 3 < CLEN) ? t + 3 : CLEN - 1;
    uint32_t c3 = up[(size_t)tn * DM];
    float uv = unpack_lo(c0);
    float dtv = unpack_hi(c0);
    sdt += dtv;
#pragma unroll
    for (int d = 0; d < DS; ++d) {
      float e = __builtin_amdgcn_exp2f(dtv * A2[d]);
      s[d] = fmaf(e, s[d], uv);
    }
    c0 = c1; c1 = c2; c2 = c3;
  }

  const size_t kk = (size_t)b * CHK + k;
#pragma unroll
  for (int j = 0; j < 4; ++j) {
    F4 fo;
#pragma unroll
    for (int i = 0; i < 4; ++i) fo.f[i] = s[j * 4 + i];
    *(float4*)(F + ((kk * 4 + j) * DM + c) * 4) = fo.v;
  }
  Sdt[kk * DM + c] = sdt;
}

// serial prefix over CHK chunks per (b,c,d); Sin (separate buffer, no alias)
// gets the carry-in for each chunk; F/Sdt prefetched FOUR iterations ahead.
__global__ __launch_bounds__(256) void scan_combine(
    const float* __restrict__ F, float* __restrict__ Sin,
    const float* __restrict__ Sdt, const float* __restrict__ A2t) {
  const int t = blockIdx.x * 256 + threadIdx.x;  // flat (j,c,i)
  const int b = blockIdx.y;
  const int c = (t >> 2) & (DM - 1);
  const float A2 = A2t[t];
  const size_t stride = (size_t)DM * DS;
  const size_t base = (size_t)b * CHK * stride + t;
  const size_t sbase = (size_t)b * CHK * DM + c;

  float fb[4], sb[4];
#pragma unroll
  for (int i = 0; i < 4; ++i) {
    int ki = (i < CHK) ? i : CHK - 1;
    fb[i] = F[base + (size_t)ki * stride];
    sb[i] = Sdt[sbase + (size_t)ki * DM];
  }

  float carry = 0.f;
#pragma unroll 4
  for (int k = 0; k < CHK; ++k) {
    int kn = (k + 4 < CHK) ? k + 4 : CHK - 1;
    float fnext = F[base + (size_t)kn * stride];
    float snext = Sdt[sbase + (size_t)kn * DM];
    float p = __builtin_amdgcn_exp2f(A2 * sb[0]);
    Sin[base + (size_t)k * stride] = carry;
    carry = fmaf(p, carry, fb[0]);
    fb[0] = fb[1]; fb[1] = fb[2]; fb[2] = fb[3]; fb[3] = fnext;
    sb[0] = sb[1]; sb[1] = sb[2]; sb[2] = sb[3]; sb[3] = snext;
  }
}

__global__ __launch_bounds__(256) void scan_part3(
    const uint32_t* __restrict__ ud, const float* __restrict__ A2c,
    const float* __restrict__ cb2m, const float* __restrict__ Sin,
    float* __restrict__ out) {
  const int c = blockIdx.x * 256 + threadIdx.x;
  const int k = blockIdx.y;
  const int b = blockIdx.z;
  const int n0 = k * CLEN;

  float A2[DS], cb2[DS], s[DS];
  const size_t kk = (size_t)b * CHK + k;
#pragma unroll
  for (int j = 0; j < 4; ++j) {
    F4 ua, uc, us;
    ua.v = *(const float4*)(A2c + (size_t)c * DS + j * 4);
    uc.v = *(const float4*)(cb2m + (size_t)c * DS + j * 4);
    us.v = *(const float4*)(Sin + ((kk * 4 + j) * DM + c) * 4);
#pragma unroll
    for (int i = 0; i < 4; ++i) {
      A2[j * 4 + i] = ua.f[i];
      cb2[j * 4 + i] = uc.f[i];
      s[j * 4 + i] = us.f[i];
    }
  }

  const uint32_t* up = ud + ((size_t)b * SEQ + n0) * DM + c;
  float* op = out + ((size_t)b * SEQ + n0) * DM + c;
  uint32_t c0 = up[0];
  uint32_t c1 = up[DM];
  uint32_t c2 = up[2 * DM];

#pragma unroll 4
  for (int t = 0; t < CLEN; ++t) {
    int tn = (t + 3 < CLEN) ? t + 3 : CLEN - 1;
    uint32_t c3 = up[(size_t)tn * DM];
    float uv = unpack_lo(c0);
    float dtv = unpack_hi(c0);
    float y0 = 0.f, y1 = 0.f;
#pragma unroll
    for (int d = 0; d < DS; d += 2) {
      float e0 = __builtin_amdgcn_exp2f(dtv * A2[d]);
      float e1 = __builtin_amdgcn_exp2f(dtv * A2[d + 1]);
      s[d] = fmaf(e0, s[d], uv);
      s[d + 1] = fmaf(e1, s[d + 1], uv);
      y0 = fmaf(cb2[d], s[d], y0);
      y1 = fmaf(cb2[d + 1], s[d + 1], y1);
    }
    op[(size_t)t * DM] = y0 + y1;
    c0 = c1; c1 = c2; c2 = c3;
  }
}

extern "C" void kernel_launch(void* const* d_in, const int* in_sizes, int n_in,
                              void* d_out, int out_size, void* d_ws, size_t ws_size,
                              hipStream_t stream) {
  const float* x     = (const float*)d_in[0];
  const float* a_log = (const float*)d_in[1];
  const float* bm    = (const float*)d_in[2];
  const float* cm    = (const float*)d_in[3];
  const float* dt_w  = (const float*)d_in[4];
  const float* dt_b  = (const float*)d_in[5];
  const float* cw    = (const float*)d_in[6];
  const float* cb    = (const float*)d_in[7];
  float* out = (float*)d_out;

  char* ws = (char*)d_ws;
  // region [0, 34MB): xf_bf (32MB) + w_bf (2MB) during conv/gemm;
  // REUSED as Sin (16.75MB) by combine/part3 (gemm completes first, stream order).
  uint16_t* xf_bf = (uint16_t*)ws;                                   // 32 MB
  uint16_t* w_bf  = (uint16_t*)(ws + (size_t)MROWS * DM * 2);        // 2 MB
  float*    Sin   = (float*)ws;                                      // 16.75 MB (alias)
  uint32_t* ud = (uint32_t*)(ws + (size_t)MROWS * DM * 2 + (size_t)DM * DM * 2);  // 64 MB
  float* Fbuf = (float*)(ud + (size_t)MROWS * DM);                   // 16.75 MB
  float* Sdt  = Fbuf + (size_t)BSZ * CHK * DM * DS;                  // 1 MB
  float* A2c  = Sdt + (size_t)BSZ * CHK * DM;                        // 64 KB
  float* A2t  = A2c + (size_t)DM * DS;                               // 64 KB
  float* cb2  = A2t + (size_t)DM * DS;                               // 64 KB

  hipLaunchKernelGGL(wprep_kernel, dim3(DM * DM / 1024), dim3(256), 0, stream,
                     dt_w, w_bf);
  hipLaunchKernelGGL(aprep_kernel, dim3(DM * DS / 256), dim3(256), 0, stream,
                     a_log, bm, cm, A2c, A2t, cb2);
  hipLaunchKernelGGL(conv_kernel, dim3(MROWS * DM / 1024), dim3(256), 0, stream,
                     x, cw, cb, xf_bf);
  hipLaunchKernelGGL(gemm_kernel, dim3(DM / BN, MROWS / BM), dim3(512), 0,
                     stream, xf_bf, w_bf, dt_b, ud);
  hipLaunchKernelGGL(scan_part1, dim3(DM / 256, CHK, BSZ), dim3(256), 0, stream,
                     ud, A2c, Fbuf, Sdt);
  hipLaunchKernelGGL(scan_combine, dim3(DM * DS / 256, BSZ), dim3(256), 0,
                     stream, Fbuf, Sin, Sdt, A2t);
  hipLaunchKernelGGL(scan_part3, dim3(DM / 256, CHK, BSZ), dim3(256), 0, stream,
                     ud, A2c, cb2, Sin, out);
}

// Round 3
// 272.488 us; speedup vs baseline: 1.3801x; 1.3801x over previous
//
#include <hip/hip_runtime.h>
#include <stdint.h>

#define BSZ 8
#define SEQ 2048
#define DM 1024
#define DS 16
#define MROWS (BSZ * SEQ)  // 16384
#define CHK 32             // chunks over SEQ
#define CLEN (SEQ / CHK)   // 64 steps per chunk
#define LOG2E 1.4426950408889634f

typedef __bf16 bf16x8 __attribute__((ext_vector_type(8)));
typedef float f32x4 __attribute__((ext_vector_type(4)));

union F4 { float4 v; float f[4]; };

// round-to-nearest-even fp32 -> bf16 (bit pattern)
__device__ __forceinline__ uint16_t f2bf(float f) {
  uint32_t u = __float_as_uint(f);
  u += 0x7FFFu + ((u >> 16) & 1u);
  return (uint16_t)(u >> 16);
}

// pack two floats as f16 pair in a uint32 (a = lo, b = hi)
__device__ __forceinline__ uint32_t pack_h2(float a, float b) {
  _Float16 ha = (_Float16)a, hb = (_Float16)b;
  uint16_t ua = __builtin_bit_cast(uint16_t, ha);
  uint16_t ub = __builtin_bit_cast(uint16_t, hb);
  return (uint32_t)ua | ((uint32_t)ub << 16);
}
__device__ __forceinline__ float unpack_lo(uint32_t v) {
  return (float)__builtin_bit_cast(_Float16, (uint16_t)(v & 0xffffu));
}
__device__ __forceinline__ float unpack_hi(uint32_t v) {
  return (float)__builtin_bit_cast(_Float16, (uint16_t)(v >> 16));
}

// async global->LDS, 16B per lane; LDS base must be wave-uniform.
__device__ __forceinline__ void async_cp16(const void* g, void* l) {
  __builtin_amdgcn_global_load_lds(
      (const __attribute__((address_space(1))) uint32_t*)(uintptr_t)g,
      (__attribute__((address_space(3))) uint32_t*)(uint32_t)(uintptr_t)l,
      16, 0, 0);
}

// ---------------- fused prep: dt_w fp32->bf16  +  scan params ----------------
// blocks [0, 1024): wprep (DM*DM/4 elements, 4/thread)
// blocks [1024, 1088): aprep (DM*DS elements, 1/thread)
__global__ __launch_bounds__(256) void prep_kernel(
    const float* __restrict__ w, uint16_t* __restrict__ wb,
    const float* __restrict__ a_log, const float* __restrict__ bm,
    const float* __restrict__ cm, float* __restrict__ A2c,
    float* __restrict__ A2t, float* __restrict__ cb2) {
  const int blk = blockIdx.x;
  if (blk < DM * DM / 1024) {
    int t = blk * 256 + threadIdx.x;
    F4 u; u.v = *(const float4*)(w + (size_t)t * 4);
    uint32_t lo = f2bf(u.f[0]) | ((uint32_t)f2bf(u.f[1]) << 16);
    uint32_t hi = f2bf(u.f[2]) | ((uint32_t)f2bf(u.f[3]) << 16);
    *(uint2*)(wb + (size_t)t * 4) = make_uint2(lo, hi);
  } else {
    int e = (blk - DM * DM / 1024) * 256 + threadIdx.x;  // [0, DM*DS)
    float a = a_log[e];
    float A2 = -log1pf(__expf(a)) * LOG2E;
    A2c[e] = A2;
    cb2[e] = bm[e] * cm[e];
    int c = e >> 4, d = e & 15;
    int j = d >> 2, i = d & 3;
    A2t[((size_t)j * DM + c) * 4 + i] = A2;
  }
}

// ---------------- depthwise conv k=3 pad=1 -> bf16 xf ----------------
__global__ __launch_bounds__(256) void conv_kernel(
    const float* __restrict__ x, const float* __restrict__ cw,
    const float* __restrict__ cb, uint16_t* __restrict__ xf) {
  int t = blockIdx.x * 256 + threadIdx.x;  // MROWS*DM/4 threads
  int cg = t & (DM / 4 - 1);
  int bn = t >> 8;
  int n = bn & (SEQ - 1);
  int c0 = cg * 4;
  const float* row = x + (size_t)bn * DM + c0;
  F4 xm, xc, xp;
  xm.v = make_float4(0.f, 0.f, 0.f, 0.f);
  xp.v = make_float4(0.f, 0.f, 0.f, 0.f);
  xc.v = *(const float4*)row;
  if (n > 0)       xm.v = *(const float4*)(row - DM);
  if (n < SEQ - 1) xp.v = *(const float4*)(row + DM);
  uint16_t o[4];
#pragma unroll
  for (int j = 0; j < 4; ++j) {
    int c = c0 + j;
    float v = cw[c * 3 + 0] * xm.f[j] + cw[c * 3 + 1] * xc.f[j] +
              cw[c * 3 + 2] * xp.f[j] + cb[c];
    o[j] = f2bf(v);
  }
  uint32_t lo = o[0] | ((uint32_t)o[1] << 16);
  uint32_t hi = o[2] | ((uint32_t)o[3] << 16);
  *(uint2*)(xf + (size_t)bn * DM + c0) = make_uint2(lo, hi);
}

// ---------------- dt GEMM + fused epilogue -> packed (u, dt) f16x2 ----------------
// NT GEMM, 128x128 tile, BK=64, 4 waves 2x2, 16x16x32 bf16 MFMA.
// (PROVEN round-1 structure: 57 us, FETCH=ideal, 0 bank conflicts, 124 VGPR.
//  The 256x256 8-wave variant spilled: VGPR capped at 128 by the allocator,
//  scratch traffic doubled WRITE_SIZE -> reverted.)
// LDS k-chunk XOR swizzle kills the 128B-stride bank conflict.
// Epilogue xf comes from a REGISTER STASH captured out of the As tile at
// kt == n0 + wn*64 (output cols index A's K dim) -> no global re-read of A.
// XCD-aware bijective block swizzle: nwg=1024, 8 XCDs -> XCD j owns the
// contiguous logical chunk [j*128, (j+1)*128) = 16 m-panels x 8 n-blocks,
// so the 8 blocks sharing an A panel hit the SAME per-XCD L2.
__global__ __launch_bounds__(256) void gemm_kernel(
    const uint16_t* __restrict__ A,   // MROWS x DM bf16 (xf)
    const uint16_t* __restrict__ B,   // DM x DM bf16 (dt_w)
    const float* __restrict__ bias,   // DM (dt_b)
    uint32_t* __restrict__ ud) {      // MROWS x DM packed f16x2 (u, dt)
  __shared__ __align__(16) uint16_t As[128 * 64];
  __shared__ __align__(16) uint16_t Bs[128 * 64];
  const int tid = threadIdx.x;
  const int w = tid >> 6;
  const int L = tid & 63;
  const int wm = w & 1, wn = w >> 1;
  const int lane15 = L & 15, q = L >> 4;

  // XCD swizzle: hardware round-robins flat id across 8 XCDs.
  const int flat = blockIdx.y * gridDim.x + blockIdx.x;      // [0, 1024)
  const int swz  = (flat & 7) * ((MROWS / 128 * DM / 128) / 8) + (flat >> 3);
  const int m0 = (swz >> 3) * 128;   // 128 m-panels
  const int n0 = (swz & 7) * 128;    // 8 n-blocks

  const int lr = L >> 3;                  // row-in-8 for staging
  const int lc = (((L & 7) ^ lr)) * 8;    // swizzled source k-chunk (8 bf16 = 16B)
  const int r7 = lane15 & 7;              // reader row&7

  f32x4 acc[4][4] = {};
  uint32_t xst[4][4][2];                  // [mi][ni][rpair]: bf16 r-even lo, r-odd hi
  const int ktmatch = n0 + wn * 64;       // wave-uniform

  for (int kt = 0; kt < DM; kt += 64) {
#pragma unroll
    for (int r = 0; r < 4; ++r) {
      int R = (r * 4 + w) * 8;  // wave-uniform LDS base
      async_cp16(A + (size_t)(m0 + R + lr) * DM + kt + lc, &As[R * 64]);
    }
#pragma unroll
    for (int r = 0; r < 4; ++r) {
      int R = (r * 4 + w) * 8;
      async_cp16(B + (size_t)(n0 + R + lr) * DM + kt + lc, &Bs[R * 64]);
    }
    __syncthreads();  // drains vmcnt -> LDS tiles visible

    if (kt == ktmatch) {  // wave-uniform branch: capture xf for the epilogue
#pragma unroll
      for (int mi = 0; mi < 4; ++mi)
#pragma unroll
        for (int ni = 0; ni < 4; ++ni)
#pragma unroll
          for (int rp = 0; rp < 2; ++rp) {
            int row0 = wm * 64 + mi * 16 + q * 4 + rp * 2;
            int row1 = row0 + 1;
            int cc = ni * 16 + lane15;  // in [0,64)
            uint32_t e0 = As[row0 * 64 + (((cc >> 3) ^ (row0 & 7)) << 3) + (cc & 7)];
            uint32_t e1 = As[row1 * 64 + (((cc >> 3) ^ (row1 & 7)) << 3) + (cc & 7)];
            xst[mi][ni][rp] = e0 | (e1 << 16);
          }
    }

#pragma unroll
    for (int ks = 0; ks < 64; ks += 32) {
      bf16x8 af[4], bfr[4];
      const int jbase = ks >> 3;
#pragma unroll
      for (int mi = 0; mi < 4; ++mi)
        af[mi] = *(const bf16x8*)(As + (wm * 64 + mi * 16 + lane15) * 64 +
                                  (((jbase + q) ^ r7) << 3));
#pragma unroll
      for (int ni = 0; ni < 4; ++ni)
        bfr[ni] = *(const bf16x8*)(Bs + (wn * 64 + ni * 16 + lane15) * 64 +
                                   (((jbase + q) ^ r7) << 3));
#pragma unroll
      for (int mi = 0; mi < 4; ++mi)
#pragma unroll
        for (int ni = 0; ni < 4; ++ni)
          acc[mi][ni] = __builtin_amdgcn_mfma_f32_16x16x32_bf16(
              af[mi], bfr[ni], acc[mi][ni], 0, 0, 0);
    }
    __syncthreads();
  }

  // epilogue: D layout col=lane&15, row=q*4+reg. sigmoid + u=dt*xf -> (u,dt) f16x2.
#pragma unroll
  for (int ni = 0; ni < 4; ++ni) {
    int col = n0 + wn * 64 + ni * 16 + lane15;
    float db = bias[col];
#pragma unroll
    for (int mi = 0; mi < 4; ++mi) {
      int rowb = m0 + wm * 64 + mi * 16 + q * 4;
#pragma unroll
      for (int r = 0; r < 4; ++r) {
        size_t idx = (size_t)(rowb + r) * DM + col;
        float z = acc[mi][ni][r] + db;
        float dtv = 0.099f / (1.f + __expf(-z)) + 0.001f;
        uint32_t p = xst[mi][ni][r >> 1];
        uint32_t bits = (r & 1) ? (p & 0xffff0000u) : (p << 16);
        float xfv = __uint_as_float(bits);
        ud[idx] = pack_h2(dtv * xfv, dtv);
      }
    }
  }
}

// ---------------- chunked selective scan (scaled state s~) ----------------
// lane = channel; one packed uint32 (u, dt) load per step.
// F layout d-plane-major: F[(((b*CHK+k)*4 + j)*DM + c)*4 + i], d = j*4+i.
// ud stream prefetched SIX steps ahead: iteration is ~160 cyc (16 trans-rate
// exp2), HBM latency ~900 cyc -> depth 6 covers it without relying on TLP.

__global__ __launch_bounds__(256) void scan_part1(
    const uint32_t* __restrict__ ud, const float* __restrict__ A2c,
    float* __restrict__ F, float* __restrict__ Sdt) {
  const int c = blockIdx.x * 256 + threadIdx.x;
  const int k = blockIdx.y;
  const int b = blockIdx.z;
  const int n0 = k * CLEN;

  float A2[DS], s[DS];
#pragma unroll
  for (int j = 0; j < 4; ++j) {
    F4 ua; ua.v = *(const float4*)(A2c + (size_t)c * DS + j * 4);
#pragma unroll
    for (int i = 0; i < 4; ++i) {
      A2[j * 4 + i] = ua.f[i];
      s[j * 4 + i] = 0.f;
    }
  }

  const uint32_t* up = ud + ((size_t)b * SEQ + n0) * DM + c;
  uint32_t cc[6];
#pragma unroll
  for (int i = 0; i < 6; ++i) cc[i] = up[(size_t)(i < CLEN ? i : CLEN - 1) * DM];
  float sdt = 0.f;

#pragma unroll 6
  for (int t = 0; t < CLEN; ++t) {
    int tn = (t + 6 < CLEN) ? t + 6 : CLEN - 1;
    uint32_t cnext = up[(size_t)tn * DM];
    float uv = unpack_lo(cc[0]);
    float dtv = unpack_hi(cc[0]);
    sdt += dtv;
#pragma unroll
    for (int d = 0; d < DS; ++d) {
      float e = __builtin_amdgcn_exp2f(dtv * A2[d]);
      s[d] = fmaf(e, s[d], uv);
    }
#pragma unroll
    for (int i = 0; i < 5; ++i) cc[i] = cc[i + 1];
    cc[5] = cnext;
  }

  const size_t kk = (size_t)b * CHK + k;
#pragma unroll
  for (int j = 0; j < 4; ++j) {
    F4 fo;
#pragma unroll
    for (int i = 0; i < 4; ++i) fo.f[i] = s[j * 4 + i];
    *(float4*)(F + ((kk * 4 + j) * DM + c) * 4) = fo.v;
  }
  Sdt[kk * DM + c] = sdt;
}

// serial prefix over CHK chunks per (b,c,d); Sin (separate buffer, no alias)
// gets the carry-in for each chunk; F/Sdt prefetched FOUR iterations ahead.
__global__ __launch_bounds__(256) void scan_combine(
    const float* __restrict__ F, float* __restrict__ Sin,
    const float* __restrict__ Sdt, const float* __restrict__ A2t) {
  const int t = blockIdx.x * 256 + threadIdx.x;  // flat (j,c,i)
  const int b = blockIdx.y;
  const int c = (t >> 2) & (DM - 1);
  const float A2 = A2t[t];
  const size_t stride = (size_t)DM * DS;
  const size_t base = (size_t)b * CHK * stride + t;
  const size_t sbase = (size_t)b * CHK * DM + c;

  float fb[4], sb[4];
#pragma unroll
  for (int i = 0; i < 4; ++i) {
    int ki = (i < CHK) ? i : CHK - 1;
    fb[i] = F[base + (size_t)ki * stride];
    sb[i] = Sdt[sbase + (size_t)ki * DM];
  }

  float carry = 0.f;
#pragma unroll 4
  for (int k = 0; k < CHK; ++k) {
    int kn = (k + 4 < CHK) ? k + 4 : CHK - 1;
    float fnext = F[base + (size_t)kn * stride];
    float snext = Sdt[sbase + (size_t)kn * DM];
    float p = __builtin_amdgcn_exp2f(A2 * sb[0]);
    Sin[base + (size_t)k * stride] = carry;
    carry = fmaf(p, carry, fb[0]);
    fb[0] = fb[1]; fb[1] = fb[2]; fb[2] = fb[3]; fb[3] = fnext;
    sb[0] = sb[1]; sb[1] = sb[2]; sb[2] = sb[3]; sb[3] = snext;
  }
}

__global__ __launch_bounds__(256) void scan_part3(
    const uint32_t* __restrict__ ud, const float* __restrict__ A2c,
    const float* __restrict__ cb2m, const float* __restrict__ Sin,
    float* __restrict__ out) {
  const int c = blockIdx.x * 256 + threadIdx.x;
  const int k = blockIdx.y;
  const int b = blockIdx.z;
  const int n0 = k * CLEN;

  float A2[DS], cb2[DS], s[DS];
  const size_t kk = (size_t)b * CHK + k;
#pragma unroll
  for (int j = 0; j < 4; ++j) {
    F4 ua, uc, us;
    ua.v = *(const float4*)(A2c + (size_t)c * DS + j * 4);
    uc.v = *(const float4*)(cb2m + (size_t)c * DS + j * 4);
    us.v = *(const float4*)(Sin + ((kk * 4 + j) * DM + c) * 4);
#pragma unroll
    for (int i = 0; i < 4; ++i) {
      A2[j * 4 + i] = ua.f[i];
      cb2[j * 4 + i] = uc.f[i];
      s[j * 4 + i] = us.f[i];
    }
  }

  const uint32_t* up = ud + ((size_t)b * SEQ + n0) * DM + c;
  float* op = out + ((size_t)b * SEQ + n0) * DM + c;
  uint32_t cc[6];
#pragma unroll
  for (int i = 0; i < 6; ++i) cc[i] = up[(size_t)(i < CLEN ? i : CLEN - 1) * DM];

#pragma unroll 6
  for (int t = 0; t < CLEN; ++t) {
    int tn = (t + 6 < CLEN) ? t + 6 : CLEN - 1;
    uint32_t cnext = up[(size_t)tn * DM];
    float uv = unpack_lo(cc[0]);
    float dtv = unpack_hi(cc[0]);
    float y0 = 0.f, y1 = 0.f;
#pragma unroll
    for (int d = 0; d < DS; d += 2) {
      float e0 = __builtin_amdgcn_exp2f(dtv * A2[d]);
      float e1 = __builtin_amdgcn_exp2f(dtv * A2[d + 1]);
      s[d] = fmaf(e0, s[d], uv);
      s[d + 1] = fmaf(e1, s[d + 1], uv);
      y0 = fmaf(cb2[d], s[d], y0);
      y1 = fmaf(cb2[d + 1], s[d + 1], y1);
    }
    op[(size_t)t * DM] = y0 + y1;
#pragma unroll
    for (int i = 0; i < 5; ++i) cc[i] = cc[i + 1];
    cc[5] = cnext;
  }
}

extern "C" void kernel_launch(void* const* d_in, const int* in_sizes, int n_in,
                              void* d_out, int out_size, void* d_ws, size_t ws_size,
                              hipStream_t stream) {
  const float* x     = (const float*)d_in[0];
  const float* a_log = (const float*)d_in[1];
  const float* bm    = (const float*)d_in[2];
  const float* cm    = (const float*)d_in[3];
  const float* dt_w  = (const float*)d_in[4];
  const float* dt_b  = (const float*)d_in[5];
  const float* cw    = (const float*)d_in[6];
  const float* cb    = (const float*)d_in[7];
  float* out = (float*)d_out;

  char* ws = (char*)d_ws;
  // region [0, 34MB): xf_bf (32MB) + w_bf (2MB) during conv/gemm;
  // REUSED as Sin (16.75MB) by combine/part3 (gemm completes first, stream order).
  uint16_t* xf_bf = (uint16_t*)ws;                                   // 32 MB
  uint16_t* w_bf  = (uint16_t*)(ws + (size_t)MROWS * DM * 2);        // 2 MB
  float*    Sin   = (float*)ws;                                      // 16.75 MB (alias)
  uint32_t* ud = (uint32_t*)(ws + (size_t)MROWS * DM * 2 + (size_t)DM * DM * 2);  // 64 MB
  float* Fbuf = (float*)(ud + (size_t)MROWS * DM);                   // 16.75 MB
  float* Sdt  = Fbuf + (size_t)BSZ * CHK * DM * DS;                  // 1 MB
  float* A2c  = Sdt + (size_t)BSZ * CHK * DM;                        // 64 KB
  float* A2t  = A2c + (size_t)DM * DS;                               // 64 KB
  float* cb2  = A2t + (size_t)DM * DS;                               // 64 KB

  hipLaunchKernelGGL(prep_kernel, dim3(DM * DM / 1024 + DM * DS / 256), dim3(256),
                     0, stream, dt_w, w_bf, a_log, bm, cm, A2c, A2t, cb2);
  hipLaunchKernelGGL(conv_kernel, dim3(MROWS * DM / 1024), dim3(256), 0, stream,
                     x, cw, cb, xf_bf);
  hipLaunchKernelGGL(gemm_kernel, dim3(DM / 128, MROWS / 128), dim3(256), 0,
                     stream, xf_bf, w_bf, dt_b, ud);
  hipLaunchKernelGGL(scan_part1, dim3(DM / 256, CHK, BSZ), dim3(256), 0, stream,
                     ud, A2c, Fbuf, Sdt);
  hipLaunchKernelGGL(scan_combine, dim3(DM * DS / 256, BSZ), dim3(256), 0,
                     stream, Fbuf, Sin, Sdt, A2t);
  hipLaunchKernelGGL(scan_part3, dim3(DM / 256, CHK, BSZ), dim3(256), 0, stream,
                     ud, A2c, cb2, Sin, out);
}